// Round 10
// baseline (1245.700 us; speedup 1.0000x reference)
//
#include <hip/hip_runtime.h>
#include <math.h>

#define BTOT 1024
#define LEN  2048
#define T    100
#define HID  128

// time-embedding dim constants (f64 argument scaling, f32 sincos)
#define C1 0.025118864315095794
#define C2 6.309573444801933e-04
#define C3 1.5848931924611134e-05
#define C4 3.9810717055349735e-07

#define TEMB(td) \
  float d0 = sinf((float)(td)); \
  float d1 = cosf((float)((td) * C1)); \
  float d2 = sinf((float)((td) * C2)); \
  float d3 = cosf((float)((td) * C3)); \
  float d4 = sinf((float)((td) * C4));

__device__ __forceinline__ float sig(float x) { return 1.0f / (1.0f + expf(-x)); }

using v2f = __attribute__((ext_vector_type(2))) float;
__device__ __forceinline__ v2f mkv2(float a, float b) { v2f r; r.x = a; r.y = b; return r; }

// DPP-based add: x + x_from_permuted_lane (VALU pipe, not DS pipe).
template <int CTRL>
__device__ __forceinline__ float dppadd(float x) {
  int r = __builtin_amdgcn_update_dpp(0, __float_as_int(x), CTRL, 0xF, 0xF, false);
  return x + __int_as_float(r);
}
// full 64-lane sum; result valid in lane 0 (ror:4 + ror:8 covers all quads
// under either rotation convention -- validated absmax 0.0 rounds 6-8).
__device__ __forceinline__ float wred(float x) {
  x = dppadd<0xB1>(x);    // quad_perm xor1
  x = dppadd<0x4E>(x);    // quad_perm xor2
  x = dppadd<0x124>(x);   // row_ror:4
  x = dppadd<0x128>(x);   // row_ror:8
  x += __shfl_xor(x, 16);
  x += __shfl_xor(x, 32);
  return x;
}
// 8-lane-group sum (groups at lanes 8k); every lane of the group gets the sum.
// ROUND-10 FIX: third step is row_half_mirror (0x141, out[i]=in[i^7]) --
// direction-unambiguous XOR semantics. Round-9 used a single row_ror:4 whose
// rotation direction mixed half of channel q_a with half of q_b: hazard moved
// ~1e-3 (passed 0.02) but ~0.1-1% of events flipped (Output 1 absmax 1.0).
#define RED8(x) { x = dppadd<0xB1>(x); x = dppadd<0x4E>(x); x = dppadd<0x141>(x); }

// ---------------- Phase A: attention precompute (unchanged) ----------------
__global__ __attribute__((amdgpu_flat_work_group_size(256, 256), amdgpu_waves_per_eu(4, 4)))
void attn_k(const float* __restrict__ ta1,
            const float* __restrict__ ta2,
            float* __restrict__ att) {
  const int b = blockIdx.x, tid = threadIdx.x;
  const int wave = tid >> 6, lane = tid & 63;

  __shared__ float qlds[T][8];
  __shared__ float strip[4][T][8];

  if (tid < T) {
    double ct = (double)(tid + 1) * 0.1;
    TEMB(ct);
    qlds[tid][0] = d0 * 0.35355339059327373f;
    qlds[tid][1] = d1 * 0.35355339059327373f;
    qlds[tid][2] = d2 * 0.35355339059327373f;
    qlds[tid][3] = d3 * 0.35355339059327373f;
    qlds[tid][4] = d4 * 0.35355339059327373f;
  }

#define E5(i) float e##i##_0, e##i##_1, e##i##_2, e##i##_3, e##i##_4;
  E5(0) E5(1) E5(2) E5(3) E5(4) E5(5) E5(6) E5(7)
  E5(8) E5(9) E5(10) E5(11) E5(12) E5(13) E5(14) E5(15)
#undef E5
#define STAGE(i, expr) { double td_ = (double)(expr); \
    e##i##_0 = sinf((float)td_); \
    e##i##_1 = cosf((float)(td_ * C1)); \
    e##i##_2 = sinf((float)(td_ * C2)); \
    e##i##_3 = cosf((float)(td_ * C3)); \
    e##i##_4 = sinf((float)(td_ * C4)); }
  STAGE(0,  ta1[b * LEN + tid +    0])
  STAGE(1,  ta1[b * LEN + tid +  256])
  STAGE(2,  ta1[b * LEN + tid +  512])
  STAGE(3,  ta1[b * LEN + tid +  768])
  STAGE(4,  ta1[b * LEN + tid + 1024])
  STAGE(5,  ta1[b * LEN + tid + 1280])
  STAGE(6,  ta1[b * LEN + tid + 1536])
  STAGE(7,  ta1[b * LEN + tid + 1792])
  STAGE(8,  ta2[b * LEN + tid +    0])
  STAGE(9,  ta2[b * LEN + tid +  256])
  STAGE(10, ta2[b * LEN + tid +  512])
  STAGE(11, ta2[b * LEN + tid +  768])
  STAGE(12, ta2[b * LEN + tid + 1024])
  STAGE(13, ta2[b * LEN + tid + 1280])
  STAGE(14, ta2[b * LEN + tid + 1536])
  STAGE(15, ta2[b * LEN + tid + 1792])
#undef STAGE
#define PIN5(i) asm volatile("" : "+v"(e##i##_0), "+v"(e##i##_1), \
    "+v"(e##i##_2), "+v"(e##i##_3), "+v"(e##i##_4));
  PIN5(0) PIN5(1) PIN5(2) PIN5(3) PIN5(4) PIN5(5) PIN5(6) PIN5(7)
  PIN5(8) PIN5(9) PIN5(10) PIN5(11) PIN5(12) PIN5(13) PIN5(14) PIN5(15)
#undef PIN5

  __syncthreads();

  for (int t = 0; t < T; t++) {
    const float4 qv = *(const float4*)&qlds[t][0];
    const float q4 = qlds[t][4];
    float Wx = 0.f, Wy = 0.f, Wz = 0.f, Ww = 0.f, W4 = 0.f, sA = 0.f, sB = 0.f;
#define EV(i, S) { \
    float s = fmaf(qv.x, e##i##_0, fmaf(qv.y, e##i##_1, \
              fmaf(qv.z, e##i##_2, fmaf(qv.w, e##i##_3, q4 * e##i##_4)))); \
    float e = __expf(s); S += e; \
    Wx = fmaf(e, e##i##_0, Wx); Wy = fmaf(e, e##i##_1, Wy); \
    Wz = fmaf(e, e##i##_2, Wz); Ww = fmaf(e, e##i##_3, Ww); \
    W4 = fmaf(e, e##i##_4, W4); }
    EV(0, sA) EV(1, sA) EV(2, sA) EV(3, sA)
    EV(4, sA) EV(5, sA) EV(6, sA) EV(7, sA)
    EV(8, sB) EV(9, sB) EV(10, sB) EV(11, sB)
    EV(12, sB) EV(13, sB) EV(14, sB) EV(15, sB)
#undef EV

    float r0 = wred(Wx), r1 = wred(Wy), r2 = wred(Wz), r3 = wred(Ww);
    float r4 = wred(W4), r5 = wred(sA), r6 = wred(sB);
    if (lane == 0) {
      *(float4*)&strip[wave][t][0] = make_float4(r0, r1, r2, r3);
      strip[wave][t][4] = r4; strip[wave][t][5] = r5; strip[wave][t][6] = r6;
    }
  }
  __syncthreads();

  if (tid < T) {
    float4 a0 = *(float4*)&strip[0][tid][0], b0 = *(float4*)&strip[0][tid][4];
    float4 a1 = *(float4*)&strip[1][tid][0], b1 = *(float4*)&strip[1][tid][4];
    float4 a2 = *(float4*)&strip[2][tid][0], b2 = *(float4*)&strip[2][tid][4];
    float4 a3 = *(float4*)&strip[3][tid][0], b3 = *(float4*)&strip[3][tid][4];
    float f0 = a0.x + a1.x + a2.x + a3.x;
    float f1 = a0.y + a1.y + a2.y + a3.y;
    float f2 = a0.z + a1.z + a2.z + a3.z;
    float f3 = a0.w + a1.w + a2.w + a3.w;
    float f4 = b0.x + b1.x + b2.x + b3.x;
    float f5 = b0.y + b1.y + b2.y + b3.y;
    float f6 = b0.z + b1.z + b2.z + b3.z;
    float inv = 1.0f / (f5 + f6);
    float* o8 = &att[(size_t)b * (T * 8) + (size_t)tid * 8];
    o8[0] = f0 * inv; o8[1] = f1 * inv; o8[2] = f2 * inv;
    o8[3] = f3 * inv; o8[4] = f4 * inv;
    o8[5] = 0.f; o8[6] = f5 * inv; o8[7] = f6 * inv;
  }
}

// ---------------- Phase B: LSTM, R=4 rows/thread (DS-read-minimized) ----------------
// Thread (q,s) = channel q's 4 gate rows {q,q+128,q+256,q+384} x 20-col
// segment s of the 160-padded x vector: 5 ds_read_b128 x 4 batches = 20
// reads/thread/t (320/CU/t vs round-8's 1216 -- the measured DS-throughput
// bottleneck, 1216 x 12cyc = 6.6us/t matched 6.45 measured). Lane s==0 holds
// all 4 gates after RED8 -> cell update in-register (cx persists), head via
// precomputed wv = w2^T.w1 -> one phase and one barrier eliminated.
__device__ __forceinline__ float wc(const float* Wih, const float* Whh, int row, int e) {
  return (e < 21) ? Wih[row * 21 + e]
       : (e < 24) ? 0.f
       : (e < 152) ? Whh[row * HID + (e - 24)]
       : 0.f;
}

#define XE(tb, b, e) (((tb) * 4 + (b)) * 160 + (e))

__global__ __attribute__((amdgpu_flat_work_group_size(1024, 1024), amdgpu_waves_per_eu(4, 4)))
void lstm_k(const float* __restrict__ att,
            const float* __restrict__ u,
            const float* __restrict__ Wih,
            const float* __restrict__ Whh,
            const float* __restrict__ bih,
            const float* __restrict__ bhh,
            const float* __restrict__ w1g,
            const float* __restrict__ b1g,
            const float* __restrict__ w2g,
            const float* __restrict__ b2g,
            float* __restrict__ out) {
  const int tid = threadIdx.x;
  const int bg = blockIdx.x * 4;
  const int q = tid >> 3, s = tid & 7;       // channel, column-segment
  const int wave = tid >> 6, lane = tid & 63;

  __shared__ float4 xls4[2][4][40];          // double-buffered [x(21)|pad|hx(128)|pad] per batch
  __shared__ float4 red4[2][4][4];           // per-wave head partials [buf][batch][16 floats]
  __shared__ int stL[2][4], stD[2][4], stH[2][4];
  float* xf = (float*)xls4;
  float* rf = (float*)red4;

  // 40 v2f weights: gate g (row q+128g), columns 20s..20s+19 as pairs
#define WD(g, c) v2f w##g##_##c = mkv2(wc(Wih, Whh, q + 128 * (g), 20 * s + 2 * (c)), \
                                       wc(Wih, Whh, q + 128 * (g), 20 * s + 2 * (c) + 1));
#define WR(g) WD(g, 0) WD(g, 1) WD(g, 2) WD(g, 3) WD(g, 4) WD(g, 5) WD(g, 6) WD(g, 7) WD(g, 8) WD(g, 9)
  WR(0) WR(1) WR(2) WR(3)
#undef WR
#undef WD
#define PW(g) asm volatile("" : "+v"(w##g##_0), "+v"(w##g##_1), "+v"(w##g##_2), \
    "+v"(w##g##_3), "+v"(w##g##_4), "+v"(w##g##_5), "+v"(w##g##_6), "+v"(w##g##_7), \
    "+v"(w##g##_8), "+v"(w##g##_9));
  PW(0) PW(1) PW(2) PW(3)
#undef PW

  float bb0 = bih[q] + bhh[q];
  float bb1 = bih[q + 128] + bhh[q + 128];
  float bb2 = bih[q + 256] + bhh[q + 256];
  float bb3 = bih[q + 384] + bhh[q + 384];
  float wv = 0.f;
#pragma unroll
  for (int j = 0; j < 5; j++) wv = fmaf(w2g[j], w1g[j * HID + q], wv);
  float hconst = b2g[0];
#pragma unroll
  for (int j = 0; j < 5; j++) hconst = fmaf(w2g[j], b1g[j], hconst);
  asm volatile("" : "+v"(bb0), "+v"(bb1), "+v"(bb2), "+v"(bb3), "+v"(wv));
  float cx0 = 0.f, cx1 = 0.f, cx2 = 0.f, cx3 = 0.f;

  for (int i = tid; i < 2 * 4 * 160; i += 1024) xf[i] = 0.f;
  if (tid < 4) { stL[0][tid] = 0; stD[0][tid] = 0; stH[0][tid] = 0; }
  __syncthreads();

  // x(t=0) into buffer 0: att + ct_emb(0.1); m_emb stays 0 (no event yet)
  if (tid < 32) {
    int b = tid >> 3, j = tid & 7;
    xf[XE(0, b, j)] = att[(size_t)(bg + b) * (T * 8) + j];
  } else if (tid >= 64 && tid < 84) {
    int s2 = tid - 64, b = s2 / 5, j = s2 % 5;
    TEMB(0.1);
    xf[XE(0, b, 16 + j)] = (j == 0) ? d0 : (j == 1) ? d1 : (j == 2) ? d2 : (j == 3) ? d3 : d4;
  }
  __syncthreads();

#define FMS(g, a) \
  a = __builtin_elementwise_fma(w##g##_0, mkv2(u0.x, u0.y), a); \
  a = __builtin_elementwise_fma(w##g##_1, mkv2(u0.z, u0.w), a); \
  a = __builtin_elementwise_fma(w##g##_2, mkv2(u1.x, u1.y), a); \
  a = __builtin_elementwise_fma(w##g##_3, mkv2(u1.z, u1.w), a); \
  a = __builtin_elementwise_fma(w##g##_4, mkv2(u2.x, u2.y), a); \
  a = __builtin_elementwise_fma(w##g##_5, mkv2(u2.z, u2.w), a); \
  a = __builtin_elementwise_fma(w##g##_6, mkv2(u3.x, u3.y), a); \
  a = __builtin_elementwise_fma(w##g##_7, mkv2(u3.z, u3.w), a); \
  a = __builtin_elementwise_fma(w##g##_8, mkv2(u4.x, u4.y), a); \
  a = __builtin_elementwise_fma(w##g##_9, mkv2(u4.z, u4.w), a);

#define BATCH(b, s0, s1, s2n, s3n) { \
  const float4* xp = &xls4[tb][b][s * 5]; \
  float4 u0 = xp[0], u1 = xp[1], u2 = xp[2], u3 = xp[3], u4 = xp[4]; \
  v2f a0 = mkv2(0.f, 0.f), a1 = a0, a2 = a0, a3 = a0; \
  FMS(0, a0) FMS(1, a1) FMS(2, a2) FMS(3, a3) \
  s0 = a0.x + a0.y; s1 = a1.x + a1.y; s2n = a2.x + a2.y; s3n = a3.x + a3.y; }

#define CELL(b, cxv) { \
  float gi = g0##b + bb0, gf = g1##b + bb1, gG = g2##b + bb2, go = g3##b + bb3; \
  cxv = sig(gf) * cxv + sig(gi) * tanhf(gG); \
  float hn = sig(go) * tanhf(cxv); \
  xf[XE(tb1, b, 24 + q)] = hn; \
  pb##b = wv * hn; }

#define CALCEV(bb) \
    float4 r0 = red4[tb][bb][0], r1 = red4[tb][bb][1], \
           r2 = red4[tb][bb][2], r3 = red4[tb][bb][3]; \
    float z_ = hconst + (((r0.x + r0.y) + (r0.z + r0.w)) + ((r1.x + r1.y) + (r1.z + r1.w))) \
                      + (((r2.x + r2.y) + (r2.z + r2.w)) + ((r3.x + r3.y) + (r3.z + r3.w))); \
    float hz_ = 1.f / (1.f + expf(-z_)); \
    int ev_ = (u[(size_t)(bg + (bb)) * T + t] < hz_) ? 1 : 0; \
    int lastp_ = ev_ ? (t + 1) : stL[tb][bb]; \
    int hasp_ = stH[tb][bb] | ev_; \
    int dynp_ = ev_ ? 0 : (stD[tb][bb] + 1);

  for (int t = 0; t < T; t++) {
    const int tb = t & 1, tb1 = tb ^ 1;

    // ---- P1: gates for 4 rows x 4 batches (20 ds_read_b128, 160 pk_fma) ----
    float g00, g10, g20, g30, g01, g11, g21, g31,
          g02, g12, g22, g32, g03, g13, g23, g33;
    BATCH(0, g00, g10, g20, g30)
    BATCH(1, g01, g11, g21, g31)
    BATCH(2, g02, g12, g22, g32)
    BATCH(3, g03, g13, g23, g33)
    RED8(g00) RED8(g10) RED8(g20) RED8(g30)
    RED8(g01) RED8(g11) RED8(g21) RED8(g31)
    RED8(g02) RED8(g12) RED8(g22) RED8(g32)
    RED8(g03) RED8(g13) RED8(g23) RED8(g33)

    float pb0 = 0.f, pb1 = 0.f, pb2 = 0.f, pb3 = 0.f;
    if (s == 0) {            // lane holds complete i,f,g,o for channel q
      CELL(0, cx0) CELL(1, cx1) CELL(2, cx2) CELL(3, cx3)
    }
    pb0 = wred(pb0); pb1 = wred(pb1); pb2 = wred(pb2); pb3 = wred(pb3);
    if (lane == 0) {
      rf[(tb * 4 + 0) * 16 + wave] = pb0;
      rf[(tb * 4 + 1) * 16 + wave] = pb1;
      rf[(tb * 4 + 2) * 16 + wave] = pb2;
      rf[(tb * 4 + 3) * 16 + wave] = pb3;
    }
    __syncthreads();

    // ---- P3: hazard/event finalize + build x(t+1) (redundant CALCEV) ----
    if (tid < 4) {
      int b = tid;
      CALCEV(b);
      out[(size_t)t * BTOT + bg + b] = hz_;
      out[(size_t)T * BTOT + (size_t)t * BTOT + bg + b] = ev_ ? 1.f : 0.f;
      stL[tb1][b] = lastp_; stH[tb1][b] = hasp_; stD[tb1][b] = dynp_;
    }
    if (t < T - 1) {
      if (tid < 32) {
        int b = tid >> 3, j = tid & 7;
        xf[XE(tb1, b, j)] = att[(size_t)(bg + b) * (T * 8) + (size_t)(t + 1) * 8 + j];
      } else if (tid < 52) {
        int s2 = tid - 32, b = s2 / 5, j = s2 % 5;
        CALCEV(b);
        float v = 0.f;
        if (hasp_) {
          double td = (double)lastp_ * 0.1;
          TEMB(td);
          v = (j == 0) ? d0 : (j == 1) ? d1 : (j == 2) ? d2 : (j == 3) ? d3 : d4;
        }
        xf[XE(tb1, b, 8 + j)] = v;
      } else if (tid < 64) {
        int s2 = tid - 52, b = s2 / 3, j = s2 % 3;
        CALCEV(b);
        xf[XE(tb1, b, 13 + j)] = (j == 0 && hasp_) ? 1.f : 0.f;
      } else if (tid < 84) {
        int s2 = tid - 64, b = s2 / 5, j = s2 % 5;
        CALCEV(b);
        double td = (double)(dynp_ + 1) * 0.1;
        TEMB(td);
        xf[XE(tb1, b, 16 + j)] =
            (j == 0) ? d0 : (j == 1) ? d1 : (j == 2) ? d2 : (j == 3) ? d3 : d4;
      }
    }
    __syncthreads();
  }
#undef CALCEV
#undef CELL
#undef BATCH
#undef FMS
}

extern "C" void kernel_launch(void* const* d_in, const int* in_sizes, int n_in,
                              void* d_out, int out_size, void* d_ws, size_t ws_size,
                              hipStream_t stream) {
  const float* ta1 = (const float*)d_in[0];
  const float* ta2 = (const float*)d_in[1];
  const float* u   = (const float*)d_in[2];
  const float* Wih = (const float*)d_in[3];
  const float* Whh = (const float*)d_in[4];
  const float* bih = (const float*)d_in[5];
  const float* bhh = (const float*)d_in[6];
  const float* w1  = (const float*)d_in[7];
  const float* b1  = (const float*)d_in[8];
  const float* w2  = (const float*)d_in[9];
  const float* b2  = (const float*)d_in[10];
  float* out = (float*)d_out;
  float* att = (float*)d_ws;   // 1024*100*8 floats = 3.28 MB scratch

  attn_k<<<dim3(BTOT), dim3(256), 0, stream>>>(ta1, ta2, att);
  lstm_k<<<dim3(BTOT / 4), dim3(1024), 0, stream>>>(att, u, Wih, Whh, bih, bhh,
                                                    w1, b1, w2, b2, out);
}